// Round 10
// baseline (105.589 us; speedup 1.0000x reference)
//
#include <hip/hip_runtime.h>
#include <hip/hip_bf16.h>

// Problem constants: B=32, T=256, D=512, P=20
#define BB 32
#define TT 256
#define DD 512
#define PP 20
#define EPSF 1e-12f
#define BTP (BB * TT * PP)   // 163840

typedef __attribute__((ext_vector_type(8))) short short8;
typedef __attribute__((ext_vector_type(4))) float f32x4;

__device__ inline unsigned short f2bf(float f) {
    unsigned u = __float_as_uint(f);
    u += 0x7fffu + ((u >> 16) & 1u);          // round-to-nearest-even
    return (unsigned short)(u >> 16);
}
__device__ inline unsigned pk2(float lo, float hi) {
    __hip_bfloat162 h = __float22bfloat162_rn(float2{lo, hi});
    union { __hip_bfloat162 h; unsigned u; } c;
    c.h = h;
    return c.u;
}
__device__ inline float bf2f(unsigned s) {    // s = 16-bit bf16 payload
    return __uint_as_float(s << 16);
}

union U8 { short8 s; uint4 u; };

// ---------------------------------------------------------------------------
// K1: per-row inverse L2 norms; emit nb_bf/na_bf, zero q, build W2.
// grid = B*T/4 blocks of 256 thr (1 wave = 1 row).   [round-8 verbatim]
// ---------------------------------------------------------------------------
__global__ __launch_bounds__(256)
void k_prep(const float* __restrict__ a, const float* __restrict__ b,
            const float* __restrict__ W,
            unsigned short* __restrict__ na_bf,
            unsigned short* __restrict__ nb_bf,
            float* __restrict__ q, unsigned short* __restrict__ W2) {
    const int row  = blockIdx.x * 4 + (threadIdx.x >> 6);
    const int lane = threadIdx.x & 63;
    const float4* pa = (const float4*)(a + (size_t)row * DD);
    const float4* pb = (const float4*)(b + (size_t)row * DD);
    float4 a0 = pa[2 * lane], a1 = pa[2 * lane + 1];
    float4 b0 = pb[2 * lane], b1 = pb[2 * lane + 1];
    float sa = a0.x * a0.x + a0.y * a0.y + a0.z * a0.z + a0.w * a0.w
             + a1.x * a1.x + a1.y * a1.y + a1.z * a1.z + a1.w * a1.w;
    float sb = b0.x * b0.x + b0.y * b0.y + b0.z * b0.z + b0.w * b0.w
             + b1.x * b1.x + b1.y * b1.y + b1.z * b1.z + b1.w * b1.w;
#pragma unroll
    for (int off = 1; off < 64; off <<= 1) {
        sa += __shfl_xor(sa, off);
        sb += __shfl_xor(sb, off);
    }
    const float ia_ = rsqrtf(fmaxf(sa, EPSF));
    const float ib_ = rsqrtf(fmaxf(sb, EPSF));
    uint4 oa, ob;
    oa.x = pk2(a0.x * ia_, a0.y * ia_);
    oa.y = pk2(a0.z * ia_, a0.w * ia_);
    oa.z = pk2(a1.x * ia_, a1.y * ia_);
    oa.w = pk2(a1.z * ia_, a1.w * ia_);
    ob.x = pk2(b0.x * ib_, b0.y * ib_);
    ob.y = pk2(b0.z * ib_, b0.w * ib_);
    ob.z = pk2(b1.x * ib_, b1.y * ib_);
    ob.w = pk2(b1.z * ib_, b1.w * ib_);
    *(uint4*)(na_bf + (size_t)row * DD + 8 * lane) = oa;
    *(uint4*)(nb_bf + (size_t)row * DD + 8 * lane) = ob;
    if (lane < 2) {
        const int i2 = 2 * row + lane;       // covers 0 .. 16383 = B*D
        q[i2] = 0.f;
        const float w = (i2 < PP * DD) ? W[i2] : 0.f;
        W2[i2] = f2bf(w * w);
    }
}

// ---------------------------------------------------------------------------
// K2: G = nb nb^T  (64x64 tile, BK=64, reg-prefetch) — DOUBLE-BUFFERED LDS:
// one __syncthreads per K-iter (was 2).  Same staged bits, same MFMA order
// (k ascending) -> bit-identical G.  grid (4,4,32), 256 thr.
// ---------------------------------------------------------------------------
__global__ __launch_bounds__(256)
void k_gemm_g(const unsigned short* __restrict__ nb,
              unsigned short* __restrict__ G) {
    const int bz  = blockIdx.z;
    const int tid = threadIdx.x;
    const int t0 = blockIdx.y * 64;
    const int s0 = blockIdx.x * 64;
    __shared__ __align__(16) unsigned short As[2][64 * 72];
    __shared__ __align__(16) unsigned short Bs[2][64 * 72];

    const int wave = tid >> 6, lane = tid & 63;
    const int quad = lane >> 4, ln = lane & 15;
    const int wm = wave >> 1, wn = wave & 1;

    const unsigned short* nbb = nb + (size_t)bz * TT * DD;

    const int lr  = tid >> 2;          // 0..63 (staging row)
    const int c16 = (tid & 3) * 16;    // 0,16,32,48 (staging col)

    f32x4 acc[2][2];
#pragma unroll
    for (int i = 0; i < 2; ++i)
#pragma unroll
        for (int j = 0; j < 2; ++j)
#pragma unroll
            for (int r = 0; r < 4; ++r) acc[i][j][r] = 0.f;

    // tile 0 -> regs -> buf0
    uint4 pa0 = *(const uint4*)(nbb + (size_t)(t0 + lr) * DD + c16);
    uint4 pa1 = *(const uint4*)(nbb + (size_t)(t0 + lr) * DD + c16 + 8);
    uint4 pb0 = *(const uint4*)(nbb + (size_t)(s0 + lr) * DD + c16);
    uint4 pb1 = *(const uint4*)(nbb + (size_t)(s0 + lr) * DD + c16 + 8);
    *(uint4*)&As[0][lr * 72 + c16]     = pa0;
    *(uint4*)&As[0][lr * 72 + c16 + 8] = pa1;
    *(uint4*)&Bs[0][lr * 72 + c16]     = pb0;
    *(uint4*)&Bs[0][lr * 72 + c16 + 8] = pb1;
    // prefetch tile 1 (DD/64 = 8 tiles, always exists)
    pa0 = *(const uint4*)(nbb + (size_t)(t0 + lr) * DD + 64 + c16);
    pa1 = *(const uint4*)(nbb + (size_t)(t0 + lr) * DD + 64 + c16 + 8);
    pb0 = *(const uint4*)(nbb + (size_t)(s0 + lr) * DD + 64 + c16);
    pb1 = *(const uint4*)(nbb + (size_t)(s0 + lr) * DD + 64 + c16 + 8);
    __syncthreads();

    int cur = 0;
    for (int k0 = 0; k0 < DD; k0 += 64) {
        short8 af[2][2], bfr[2][2];
#pragma unroll
        for (int h = 0; h < 2; ++h) {
            af[h][0]  = *(const short8*)&As[cur][(wm * 32 + ln) * 72 + h * 32 + quad * 8];
            af[h][1]  = *(const short8*)&As[cur][(wm * 32 + 16 + ln) * 72 + h * 32 + quad * 8];
            bfr[h][0] = *(const short8*)&Bs[cur][(wn * 32 + ln) * 72 + h * 32 + quad * 8];
            bfr[h][1] = *(const short8*)&Bs[cur][(wn * 32 + 16 + ln) * 72 + h * 32 + quad * 8];
        }
        if (k0 + 64 < DD) {
            const int nxt = cur ^ 1;
            *(uint4*)&As[nxt][lr * 72 + c16]     = pa0;
            *(uint4*)&As[nxt][lr * 72 + c16 + 8] = pa1;
            *(uint4*)&Bs[nxt][lr * 72 + c16]     = pb0;
            *(uint4*)&Bs[nxt][lr * 72 + c16 + 8] = pb1;
            if (k0 + 128 < DD) {
                pa0 = *(const uint4*)(nbb + (size_t)(t0 + lr) * DD + k0 + 128 + c16);
                pa1 = *(const uint4*)(nbb + (size_t)(t0 + lr) * DD + k0 + 128 + c16 + 8);
                pb0 = *(const uint4*)(nbb + (size_t)(s0 + lr) * DD + k0 + 128 + c16);
                pb1 = *(const uint4*)(nbb + (size_t)(s0 + lr) * DD + k0 + 128 + c16 + 8);
            }
        }
#pragma unroll
        for (int h = 0; h < 2; ++h)
#pragma unroll
            for (int i = 0; i < 2; ++i)
#pragma unroll
                for (int j = 0; j < 2; ++j)
                    acc[i][j] = __builtin_amdgcn_mfma_f32_16x16x32_bf16(
                        af[h][i], bfr[h][j], acc[i][j], 0, 0, 0);
        __syncthreads();
        cur ^= 1;
    }
    unsigned short* Gb = G + (size_t)bz * TT * TT;
#pragma unroll
    for (int i = 0; i < 2; ++i)
#pragma unroll
        for (int j = 0; j < 2; ++j) {
            const int col = s0 + wn * 32 + j * 16 + ln;
            const int row0 = t0 + wm * 32 + i * 16 + quad * 4;
#pragma unroll
            for (int r = 0; r < 4; r += 2) {
                const unsigned pk = pk2(acc[i][j][r], acc[i][j][r + 1]);
                Gb[(size_t)(row0 + r) * TT + col] = (unsigned short)pk;
                Gb[(size_t)(row0 + r + 1) * TT + col] = (unsigned short)(pk >> 16);
            }
        }
}

// ---------------------------------------------------------------------------
// K3: H = G na (inline B-transpose b32-pack staging, reg-prefetch), fused q
// epilogue (LDS-staged na) — DOUBLE-BUFFERED LDS: one barrier per K-iter.
// Same staged bits & MFMA order -> bit-identical H/q.
// __launch_bounds__(256,4): 4 blocks/CU.  grid: (D/64, T/64, B), 256 thr.
// ---------------------------------------------------------------------------
__global__ __launch_bounds__(256, 4)
void k_gemm_h(const unsigned short* __restrict__ G,
              const unsigned short* __restrict__ na,
              unsigned short* __restrict__ H, float* __restrict__ q) {
    const int bz = blockIdx.z;
    const int t0 = blockIdx.y * 64;
    const int e0 = blockIdx.x * 64;
    // AB = As0 | Bs0 | As1 | Bs1, each 64*40 shorts (2560)
    __shared__ __align__(16) unsigned short AB[4 * 64 * 40];   // 20480 B
    __shared__ float qsum[64];

    const int tid  = threadIdx.x;
    const int wave = tid >> 6, lane = tid & 63;
    const int quad = lane >> 4, ln = lane & 15;
    const int wm = wave >> 1, wn = wave & 1;

    const unsigned short* Gb  = G  + (size_t)bz * TT * TT;
    const unsigned short* nab = na + (size_t)bz * TT * DD;

    const int lr = tid >> 2;          // 0..63  (A staging row)
    const int c8 = (tid & 3) * 8;     // 0..24  (A staging col)
    const int eglow = tid & 3;
    const int spair = (tid >> 2) & 15;          // k-pair 0..15 (k = 2*spair)
    const int eg    = eglow + 4 * (tid >> 6);   // 0..7 (e-octet)

    f32x4 acc[2][2];
#pragma unroll
    for (int i = 0; i < 2; ++i)
#pragma unroll
        for (int j = 0; j < 2; ++j)
#pragma unroll
            for (int r = 0; r < 4; ++r) acc[i][j][r] = 0.f;

    // tile 0 -> regs -> buf0
    uint4 pga = *(const uint4*)(Gb + (size_t)(t0 + lr) * TT + c8);
    uint4 cva, cvb;
    if (tid < 128) {
        cva = *(const uint4*)(nab + (size_t)(2 * spair) * DD + e0 + eg * 8);
        cvb = *(const uint4*)(nab + (size_t)(2 * spair + 1) * DD + e0 + eg * 8);
    }
    {
        unsigned short* As0 = AB;
        unsigned* bp0 = (unsigned*)(AB + 2560);
        *(uint4*)&As0[lr * 40 + c8] = pga;
        if (tid < 128) {
            const int base = eg * 160 + spair;
            unsigned lo, hi;
            lo = cva.x; hi = cvb.x;
            bp0[base +   0] = (lo & 0xffffu) | (hi << 16);
            bp0[base +  20] = (lo >> 16) | (hi & 0xffff0000u);
            lo = cva.y; hi = cvb.y;
            bp0[base +  40] = (lo & 0xffffu) | (hi << 16);
            bp0[base +  60] = (lo >> 16) | (hi & 0xffff0000u);
            lo = cva.z; hi = cvb.z;
            bp0[base +  80] = (lo & 0xffffu) | (hi << 16);
            bp0[base + 100] = (lo >> 16) | (hi & 0xffff0000u);
            lo = cva.w; hi = cvb.w;
            bp0[base + 120] = (lo & 0xffffu) | (hi << 16);
            bp0[base + 140] = (lo >> 16) | (hi & 0xffff0000u);
        }
    }
    // prefetch tile 1 (TT/32 = 8 tiles, always exists)
    pga = *(const uint4*)(Gb + (size_t)(t0 + lr) * TT + 32 + c8);
    if (tid < 128) {
        cva = *(const uint4*)(nab + (size_t)(32 + 2 * spair) * DD + e0 + eg * 8);
        cvb = *(const uint4*)(nab + (size_t)(32 + 2 * spair + 1) * DD + e0 + eg * 8);
    }
    __syncthreads();

    int cur = 0;
    for (int k0 = 0; k0 < TT; k0 += 32) {
        const unsigned short* Asc = AB + cur * 5120;
        const unsigned short* Bsc = Asc + 2560;
        short8 af[2], bfr[2];
        af[0]  = *(const short8*)&Asc[(wm * 32 + ln) * 40 + quad * 8];
        af[1]  = *(const short8*)&Asc[(wm * 32 + 16 + ln) * 40 + quad * 8];
        bfr[0] = *(const short8*)&Bsc[(wn * 32 + ln) * 40 + quad * 8];
        bfr[1] = *(const short8*)&Bsc[(wn * 32 + 16 + ln) * 40 + quad * 8];
        if (k0 + 32 < TT) {
            unsigned short* Asn = AB + (cur ^ 1) * 5120;
            unsigned* bpn = (unsigned*)(Asn + 2560);
            *(uint4*)&Asn[lr * 40 + c8] = pga;
            if (tid < 128) {
                const int base = eg * 160 + spair;
                unsigned lo, hi;
                lo = cva.x; hi = cvb.x;
                bpn[base +   0] = (lo & 0xffffu) | (hi << 16);
                bpn[base +  20] = (lo >> 16) | (hi & 0xffff0000u);
                lo = cva.y; hi = cvb.y;
                bpn[base +  40] = (lo & 0xffffu) | (hi << 16);
                bpn[base +  60] = (lo >> 16) | (hi & 0xffff0000u);
                lo = cva.z; hi = cvb.z;
                bpn[base +  80] = (lo & 0xffffu) | (hi << 16);
                bpn[base + 100] = (lo >> 16) | (hi & 0xffff0000u);
                lo = cva.w; hi = cvb.w;
                bpn[base + 120] = (lo & 0xffffu) | (hi << 16);
                bpn[base + 140] = (lo >> 16) | (hi & 0xffff0000u);
            }
            if (k0 + 64 < TT) {
                pga = *(const uint4*)(Gb + (size_t)(t0 + lr) * TT + k0 + 64 + c8);
                if (tid < 128) {
                    cva = *(const uint4*)(nab + (size_t)(k0 + 64 + 2 * spair) * DD + e0 + eg * 8);
                    cvb = *(const uint4*)(nab + (size_t)(k0 + 64 + 2 * spair + 1) * DD + e0 + eg * 8);
                }
            }
        }
#pragma unroll
        for (int i = 0; i < 2; ++i)
#pragma unroll
            for (int j = 0; j < 2; ++j)
                acc[i][j] = __builtin_amdgcn_mfma_f32_16x16x32_bf16(
                    af[i], bfr[j], acc[i][j], 0, 0, 0);
        __syncthreads();
        cur ^= 1;
    }

    // epilogue: stage na[t0..t0+63][e0..e0+63] into LDS (stride 72 shorts)
    // with 2 coalesced 16B loads/thread; 9216 B fits in AB[0..5120) span.
    unsigned short* Ns = AB;
    {
        const int r0_ = tid >> 3, k8 = (tid & 7) * 8;
        *(uint4*)&Ns[r0_ * 72 + k8] =
            *(const uint4*)(nab + (size_t)(t0 + r0_) * DD + e0 + k8);
        const int c1 = tid + 256;
        const int r1_ = c1 >> 3, k8b = (c1 & 7) * 8;
        *(uint4*)&Ns[r1_ * 72 + k8b] =
            *(const uint4*)(nab + (size_t)(t0 + r1_) * DD + e0 + k8b);
    }
    if (tid < 64) qsum[tid] = 0.f;
    __syncthreads();

    unsigned short* Hb = H + (size_t)bz * TT * DD;
#pragma unroll
    for (int j = 0; j < 2; ++j) {
        const int col  = e0 + wn * 32 + j * 16 + ln;
        const int lcol = wn * 32 + j * 16 + ln;
        float qp = 0.f;
#pragma unroll
        for (int i = 0; i < 2; ++i) {
            const int row0  = t0 + wm * 32 + i * 16 + quad * 4;
            const int lrow0 = wm * 32 + i * 16 + quad * 4;
#pragma unroll
            for (int r = 0; r < 4; r += 2) {
                const float hv0 = acc[i][j][r];
                const float hv1 = acc[i][j][r + 1];
                const unsigned pk = pk2(hv0, hv1);
                Hb[(size_t)(row0 + r) * DD + col] = (unsigned short)pk;
                Hb[(size_t)(row0 + r + 1) * DD + col] = (unsigned short)(pk >> 16);
                qp = fmaf(bf2f(Ns[(lrow0 + r) * 72 + lcol]), hv0, qp);
                qp = fmaf(bf2f(Ns[(lrow0 + r + 1) * 72 + lcol]), hv1, qp);
            }
        }
        qp += __shfl_xor(qp, 16);
        qp += __shfl_xor(qp, 32);
        if (quad == 0) atomicAdd(&qsum[wn * 32 + j * 16 + ln], qp);
    }
    __syncthreads();
    if (tid < 64) atomicAdd(q + bz * DD + e0 + tid, qsum[tid]);
}

// ---------------------------------------------------------------------------
// K4: persp via MFMA, split-K over 4 waves, k-loop unrolled.
// grid: (T/16, B), 256 thr.   [round-8 verbatim]
// ---------------------------------------------------------------------------
__global__ __launch_bounds__(256)
void k_persp_mfma(const unsigned short* __restrict__ na,
                  const unsigned short* __restrict__ H,
                  const float* __restrict__ q,
                  const unsigned short* __restrict__ W2,
                  float* __restrict__ out) {
    const int b    = blockIdx.y;
    const int r0   = blockIdx.x * 16;
    const int wave = threadIdx.x >> 6;   // 0..3
    const int lane = threadIdx.x & 63;
    const int quad = lane >> 4, ln = lane & 15;
    const size_t rowbase = ((size_t)b * TT + r0 + ln) * DD;

    __shared__ float qs[DD];
    __shared__ float ps[3][64][24];      // waves 1..3 partials
    {
        const float* qb = q + (size_t)b * DD;
        float2 v = *(const float2*)(qb + 2 * threadIdx.x);
        qs[2 * threadIdx.x + 0] = rsqrtf(fmaxf(v.x, EPSF));
        qs[2 * threadIdx.x + 1] = rsqrtf(fmaxf(v.y, EPSF));
    }
    __syncthreads();

    f32x4 s1[2], s2[2], s3[2];
#pragma unroll
    for (int j = 0; j < 2; ++j)
#pragma unroll
        for (int r = 0; r < 4; ++r) { s1[j][r] = 0.f; s2[j][r] = 0.f; s3[j][r] = 0.f; }

    const int kbeg = wave * 128;
#pragma unroll
    for (int ki = 0; ki < 4; ++ki) {
        const int k0 = kbeg + ki * 32;
        const int k = k0 + quad * 8;
        uint4 au = *(const uint4*)(na + rowbase + k);
        uint4 hu = *(const uint4*)(H + rowbase + k);
        float4 q0 = *(const float4*)&qs[k];
        float4 q1 = *(const float4*)&qs[k + 4];
        const float av[8] = {bf2f(au.x & 0xffffu), bf2f(au.x >> 16),
                             bf2f(au.y & 0xffffu), bf2f(au.y >> 16),
                             bf2f(au.z & 0xffffu), bf2f(au.z >> 16),
                             bf2f(au.w & 0xffffu), bf2f(au.w >> 16)};
        const float qv[8] = {q0.x, q0.y, q0.z, q0.w, q1.x, q1.y, q1.z, q1.w};
        float hv[8] = {bf2f(hu.x & 0xffffu), bf2f(hu.x >> 16),
                       bf2f(hu.y & 0xffffu), bf2f(hu.y >> 16),
                       bf2f(hu.z & 0xffffu), bf2f(hu.z >> 16),
                       bf2f(hu.w & 0xffffu), bf2f(hu.w >> 16)};
#pragma unroll
        for (int t = 0; t < 8; ++t) hv[t] *= qv[t];
        U8 ah, aa, hh;
        ah.u.x = pk2(av[0] * hv[0], av[1] * hv[1]);
        ah.u.y = pk2(av[2] * hv[2], av[3] * hv[3]);
        ah.u.z = pk2(av[4] * hv[4], av[5] * hv[5]);
        ah.u.w = pk2(av[6] * hv[6], av[7] * hv[7]);
        aa.u.x = pk2(av[0] * av[0], av[1] * av[1]);
        aa.u.y = pk2(av[2] * av[2], av[3] * av[3]);
        aa.u.z = pk2(av[4] * av[4], av[5] * av[5]);
        aa.u.w = pk2(av[6] * av[6], av[7] * av[7]);
        hh.u.x = pk2(hv[0] * hv[0], hv[1] * hv[1]);
        hh.u.y = pk2(hv[2] * hv[2], hv[3] * hv[3]);
        hh.u.z = pk2(hv[4] * hv[4], hv[5] * hv[5]);
        hh.u.w = pk2(hv[6] * hv[6], hv[7] * hv[7]);
        short8 bw0 = *(const short8*)(W2 + (size_t)ln * DD + k);
        short8 bw1 = *(const short8*)(W2 + (size_t)(16 + ln) * DD + k);
        s1[0] = __builtin_amdgcn_mfma_f32_16x16x32_bf16(ah.s, bw0, s1[0], 0, 0, 0);
        s1[1] = __builtin_amdgcn_mfma_f32_16x16x32_bf16(ah.s, bw1, s1[1], 0, 0, 0);
        s2[0] = __builtin_amdgcn_mfma_f32_16x16x32_bf16(aa.s, bw0, s2[0], 0, 0, 0);
        s2[1] = __builtin_amdgcn_mfma_f32_16x16x32_bf16(aa.s, bw1, s2[1], 0, 0, 0);
        s3[0] = __builtin_amdgcn_mfma_f32_16x16x32_bf16(hh.s, bw0, s3[0], 0, 0, 0);
        s3[1] = __builtin_amdgcn_mfma_f32_16x16x32_bf16(hh.s, bw1, s3[1], 0, 0, 0);
    }

    if (wave >= 1) {
#pragma unroll
        for (int j = 0; j < 2; ++j)
#pragma unroll
            for (int r = 0; r < 4; ++r) {
                ps[wave - 1][lane][j * 4 + r]      = s1[j][r];
                ps[wave - 1][lane][8 + j * 4 + r]  = s2[j][r];
                ps[wave - 1][lane][16 + j * 4 + r] = s3[j][r];
            }
    }
    __syncthreads();
    if (wave == 0) {
#pragma unroll
        for (int j = 0; j < 2; ++j) {
            const int p = j * 16 + ln;
            if (p < PP) {
#pragma unroll
                for (int r = 0; r < 4; ++r) {
                    const float v1 = s1[j][r] + ps[0][lane][j * 4 + r]
                                   + ps[1][lane][j * 4 + r] + ps[2][lane][j * 4 + r];
                    const float v2 = s2[j][r] + ps[0][lane][8 + j * 4 + r]
                                   + ps[1][lane][8 + j * 4 + r] + ps[2][lane][8 + j * 4 + r];
                    const float v3 = s3[j][r] + ps[0][lane][16 + j * 4 + r]
                                   + ps[1][lane][16 + j * 4 + r] + ps[2][lane][16 + j * 4 + r];
                    const size_t row = (size_t)b * TT + r0 + quad * 4 + r;
                    const float v = v1 * rsqrtf(fmaxf(v2, EPSF))
                                       * rsqrtf(fmaxf(v3, EPSF));
                    out[row * PP + p] = v;
                    out[(size_t)BTP + row * PP + p] = v;
                }
            }
        }
    }
}

// ---------------------------------------------------------------------------
extern "C" void kernel_launch(void* const* d_in, const int* in_sizes, int n_in,
                              void* d_out, int out_size, void* d_ws, size_t ws_size,
                              hipStream_t stream) {
    (void)in_sizes; (void)n_in; (void)out_size; (void)ws_size;
    const float* a = (const float*)d_in[0];   // (B,T,D)
    const float* b = (const float*)d_in[1];   // (B,T,D)
    const float* W = (const float*)d_in[2];   // (P,D)
    float* out = (float*)d_out;

    char* ws = (char*)d_ws;
    unsigned short* nb_bf = (unsigned short*)ws;                       // 8 MB
    unsigned short* na_bf = (unsigned short*)(ws + (8u << 20));        // 8 MB
    unsigned short* G_bf  = (unsigned short*)(ws + (16u << 20));       // 4 MB
    unsigned short* H_bf  = (unsigned short*)(ws + (20u << 20));       // 8 MB
    float* q     = (float*)(ws + (28u << 20));                         // 64 KB
    unsigned short* W2 = (unsigned short*)(ws + (28u << 20) + (64u << 10)); // 32 KB

    // L1: norms + na/nb bf16 + q zero + W2 build
    k_prep<<<BB * TT / 4, 256, 0, stream>>>(a, b, W, na_bf, nb_bf, q, W2);

    // L2: G = nb nb^T   [BK=64, double-buffered LDS, 1 barrier/iter]
    dim3 gG(4, 4, BB);
    k_gemm_g<<<gG, 256, 0, stream>>>(nb_bf, G_bf);

    // L3: H = G na (double-buffered staging), fused q
    dim3 gH(DD / 64, TT / 64, BB);
    k_gemm_h<<<gH, 256, 0, stream>>>(G_bf, na_bf, H_bf, q);

    // L4: perspective outputs (invq inlined, split-K over 4 waves, unrolled)
    dim3 gP(TT / 16, BB);
    k_persp_mfma<<<gP, 256, 0, stream>>>(na_bf, H_bf, q, W2, out);
}

// Round 11
// 104.103 us; speedup vs baseline: 1.0143x; 1.0143x over previous
//
#include <hip/hip_runtime.h>
#include <hip/hip_bf16.h>

// Problem constants: B=32, T=256, D=512, P=20
#define BB 32
#define TT 256
#define DD 512
#define PP 20
#define EPSF 1e-12f
#define BTP (BB * TT * PP)   // 163840

typedef __attribute__((ext_vector_type(8))) short short8;
typedef __attribute__((ext_vector_type(4))) float f32x4;

__device__ inline unsigned short f2bf(float f) {
    unsigned u = __float_as_uint(f);
    u += 0x7fffu + ((u >> 16) & 1u);          // round-to-nearest-even
    return (unsigned short)(u >> 16);
}
__device__ inline unsigned pk2(float lo, float hi) {
    __hip_bfloat162 h = __float22bfloat162_rn(float2{lo, hi});
    union { __hip_bfloat162 h; unsigned u; } c;
    c.h = h;
    return c.u;
}
__device__ inline float bf2f(unsigned s) {    // s = 16-bit bf16 payload
    return __uint_as_float(s << 16);
}

union U8 { short8 s; uint4 u; };

// ---------------------------------------------------------------------------
// K1: b-half of prep only: per-row inverse L2 norm of b -> nb_bf, plus q-zero
// and W2 build.  (a-half rides in K2 as independent blocks.)  Same per-wave
// reduction order as the original fused prep -> nb bit-identical.
// grid = B*T/4 blocks of 256 thr (1 wave = 1 row).
// ---------------------------------------------------------------------------
__global__ __launch_bounds__(256)
void k_prep_b(const float* __restrict__ b, const float* __restrict__ W,
              unsigned short* __restrict__ nb_bf,
              float* __restrict__ q, unsigned short* __restrict__ W2) {
    const int row  = blockIdx.x * 4 + (threadIdx.x >> 6);
    const int lane = threadIdx.x & 63;
    const float4* pb = (const float4*)(b + (size_t)row * DD);
    float4 b0 = pb[2 * lane], b1 = pb[2 * lane + 1];
    float sb = b0.x * b0.x + b0.y * b0.y + b0.z * b0.z + b0.w * b0.w
             + b1.x * b1.x + b1.y * b1.y + b1.z * b1.z + b1.w * b1.w;
#pragma unroll
    for (int off = 1; off < 64; off <<= 1) sb += __shfl_xor(sb, off);
    const float ib_ = rsqrtf(fmaxf(sb, EPSF));
    uint4 ob;
    ob.x = pk2(b0.x * ib_, b0.y * ib_);
    ob.y = pk2(b0.z * ib_, b0.w * ib_);
    ob.z = pk2(b1.x * ib_, b1.y * ib_);
    ob.w = pk2(b1.z * ib_, b1.w * ib_);
    *(uint4*)(nb_bf + (size_t)row * DD + 8 * lane) = ob;
    if (lane < 2) {
        const int i2 = 2 * row + lane;       // covers 0 .. 16383 = B*D
        q[i2] = 0.f;
        const float w = (i2 < PP * DD) ? W[i2] : 0.f;
        W2[i2] = f2bf(w * w);
    }
}

// ---------------------------------------------------------------------------
// K2: MIXED launch, 1024 blocks x 256 thr (4 blocks/CU):
//   blocks 0..511   : G = nb nb^T (64x64 tile, BK=64, reg-prefetch) —
//                     round-8 k_gemm_g verbatim, 1D block decode.
//   blocks 512..1023: a-half of prep (na_bf), 16 rows/block — independent
//                     work that HIDES under G's latency-bound execution.
// NO intra-kernel producer->consumer edges: G reads nb (L1 boundary), prep_a
// reads input a; na/G are consumed only after the L2->L3 boundary.
// ---------------------------------------------------------------------------
__global__ __launch_bounds__(256)
void k_g_pa(const unsigned short* __restrict__ nb,
            const float* __restrict__ a,
            unsigned short* __restrict__ G,
            unsigned short* __restrict__ na_bf) {
    const int blk = blockIdx.x;
    const int tid = threadIdx.x;
    const int wave = tid >> 6, lane = tid & 63;

    __shared__ __align__(16) unsigned short As[64 * 72];
    __shared__ __align__(16) unsigned short Bs[64 * 72];

    if (blk >= 512) {
        // ---- prep_a: rows (blk-512)*16 .. +15 ----
        const int idx = blk - 512;
#pragma unroll 1
        for (int it = 0; it < 4; ++it) {
            const int row = idx * 16 + it * 4 + wave;
            const float4* pa = (const float4*)(a + (size_t)row * DD);
            float4 a0 = pa[2 * lane], a1 = pa[2 * lane + 1];
            float sa = a0.x * a0.x + a0.y * a0.y + a0.z * a0.z + a0.w * a0.w
                     + a1.x * a1.x + a1.y * a1.y + a1.z * a1.z + a1.w * a1.w;
#pragma unroll
            for (int off = 1; off < 64; off <<= 1) sa += __shfl_xor(sa, off);
            const float ia_ = rsqrtf(fmaxf(sa, EPSF));
            uint4 oa;
            oa.x = pk2(a0.x * ia_, a0.y * ia_);
            oa.y = pk2(a0.z * ia_, a0.w * ia_);
            oa.z = pk2(a1.x * ia_, a1.y * ia_);
            oa.w = pk2(a1.z * ia_, a1.w * ia_);
            *(uint4*)(na_bf + (size_t)row * DD + 8 * lane) = oa;
        }
        return;
    }

    // ---- G tile: round-8 k_gemm_g body, blk decodes (s,t,bz) ----
    const int bz = blk >> 4;
    const int t0 = ((blk >> 2) & 3) * 64;
    const int s0 = (blk & 3) * 64;
    const int quad = lane >> 4, ln = lane & 15;
    const int wm = wave >> 1, wn = wave & 1;

    const unsigned short* nbb = nb + (size_t)bz * TT * DD;

    const int lr  = tid >> 2;          // 0..63 (staging row)
    const int c16 = (tid & 3) * 16;    // 0,16,32,48 (staging col)

    f32x4 acc[2][2];
#pragma unroll
    for (int i = 0; i < 2; ++i)
#pragma unroll
        for (int j = 0; j < 2; ++j)
#pragma unroll
            for (int r = 0; r < 4; ++r) acc[i][j][r] = 0.f;

    uint4 pa0 = *(const uint4*)(nbb + (size_t)(t0 + lr) * DD + c16);
    uint4 pa1 = *(const uint4*)(nbb + (size_t)(t0 + lr) * DD + c16 + 8);
    uint4 pb0 = *(const uint4*)(nbb + (size_t)(s0 + lr) * DD + c16);
    uint4 pb1 = *(const uint4*)(nbb + (size_t)(s0 + lr) * DD + c16 + 8);

    for (int k0 = 0; k0 < DD; k0 += 64) {
        *(uint4*)&As[lr * 72 + c16]     = pa0;
        *(uint4*)&As[lr * 72 + c16 + 8] = pa1;
        *(uint4*)&Bs[lr * 72 + c16]     = pb0;
        *(uint4*)&Bs[lr * 72 + c16 + 8] = pb1;
        if (k0 + 64 < DD) {
            pa0 = *(const uint4*)(nbb + (size_t)(t0 + lr) * DD + k0 + 64 + c16);
            pa1 = *(const uint4*)(nbb + (size_t)(t0 + lr) * DD + k0 + 64 + c16 + 8);
            pb0 = *(const uint4*)(nbb + (size_t)(s0 + lr) * DD + k0 + 64 + c16);
            pb1 = *(const uint4*)(nbb + (size_t)(s0 + lr) * DD + k0 + 64 + c16 + 8);
        }
        __syncthreads();
        short8 af[2][2], bfr[2][2];
#pragma unroll
        for (int h = 0; h < 2; ++h) {
            af[h][0]  = *(const short8*)&As[(wm * 32 + ln) * 72 + h * 32 + quad * 8];
            af[h][1]  = *(const short8*)&As[(wm * 32 + 16 + ln) * 72 + h * 32 + quad * 8];
            bfr[h][0] = *(const short8*)&Bs[(wn * 32 + ln) * 72 + h * 32 + quad * 8];
            bfr[h][1] = *(const short8*)&Bs[(wn * 32 + 16 + ln) * 72 + h * 32 + quad * 8];
        }
#pragma unroll
        for (int h = 0; h < 2; ++h)
#pragma unroll
            for (int i = 0; i < 2; ++i)
#pragma unroll
                for (int j = 0; j < 2; ++j)
                    acc[i][j] = __builtin_amdgcn_mfma_f32_16x16x32_bf16(
                        af[h][i], bfr[h][j], acc[i][j], 0, 0, 0);
        __syncthreads();
    }
    unsigned short* Gb = G + (size_t)bz * TT * TT;
#pragma unroll
    for (int i = 0; i < 2; ++i)
#pragma unroll
        for (int j = 0; j < 2; ++j) {
            const int col = s0 + wn * 32 + j * 16 + ln;
            const int row0 = t0 + wm * 32 + i * 16 + quad * 4;
#pragma unroll
            for (int r = 0; r < 4; r += 2) {
                const unsigned pk = pk2(acc[i][j][r], acc[i][j][r + 1]);
                Gb[(size_t)(row0 + r) * TT + col] = (unsigned short)pk;
                Gb[(size_t)(row0 + r + 1) * TT + col] = (unsigned short)(pk >> 16);
            }
        }
}

// ---------------------------------------------------------------------------
// K3: H = G na (inline B-transpose b32-pack staging, reg-prefetch), fused q
// epilogue with LDS-staged na.  [round-8 verbatim, best measured]
// __launch_bounds__(256,4): 4 blocks/CU.  grid: (D/64, T/64, B), 256 thr.
// ---------------------------------------------------------------------------
__global__ __launch_bounds__(256, 4)
void k_gemm_h(const unsigned short* __restrict__ G,
              const unsigned short* __restrict__ na,
              unsigned short* __restrict__ H, float* __restrict__ q) {
    const int bz = blockIdx.z;
    const int t0 = blockIdx.y * 64;
    const int e0 = blockIdx.x * 64;
    __shared__ __align__(16) unsigned short AB[2 * 64 * 40];  // As | Bs (10240B)
    __shared__ float qsum[64];
    unsigned short* As = AB;
    unsigned short* Bs = AB + 64 * 40;

    const int tid  = threadIdx.x;
    const int wave = tid >> 6, lane = tid & 63;
    const int quad = lane >> 4, ln = lane & 15;
    const int wm = wave >> 1, wn = wave & 1;

    const unsigned short* Gb  = G  + (size_t)bz * TT * TT;
    const unsigned short* nab = na + (size_t)bz * TT * DD;

    const int lr = tid >> 2;          // 0..63  (A staging row)
    const int c8 = (tid & 3) * 8;     // 0..24  (A staging col)
    const int eglow = tid & 3;
    const int spair = (tid >> 2) & 15;          // k-pair 0..15 (k = 2*spair)
    const int eg    = eglow + 4 * (tid >> 6);   // 0..7 (e-octet)

    f32x4 acc[2][2];
#pragma unroll
    for (int i = 0; i < 2; ++i)
#pragma unroll
        for (int j = 0; j < 2; ++j)
#pragma unroll
            for (int r = 0; r < 4; ++r) acc[i][j][r] = 0.f;

    // prefetch K-tile 0
    uint4 pga = *(const uint4*)(Gb + (size_t)(t0 + lr) * TT + c8);
    uint4 cva, cvb;
    if (tid < 128) {
        cva = *(const uint4*)(nab + (size_t)(2 * spair) * DD + e0 + eg * 8);
        cvb = *(const uint4*)(nab + (size_t)(2 * spair + 1) * DD + e0 + eg * 8);
    }

    unsigned* bp = (unsigned*)Bs;
    for (int k0 = 0; k0 < TT; k0 += 32) {
        *(uint4*)&As[lr * 40 + c8] = pga;
        if (tid < 128) {
            const int base = eg * 160 + spair;   // uint idx: (eg*8)*20 + spair
            unsigned lo, hi;
            lo = cva.x; hi = cvb.x;
            bp[base +   0] = (lo & 0xffffu) | (hi << 16);
            bp[base +  20] = (lo >> 16) | (hi & 0xffff0000u);
            lo = cva.y; hi = cvb.y;
            bp[base +  40] = (lo & 0xffffu) | (hi << 16);
            bp[base +  60] = (lo >> 16) | (hi & 0xffff0000u);
            lo = cva.z; hi = cvb.z;
            bp[base +  80] = (lo & 0xffffu) | (hi << 16);
            bp[base + 100] = (lo >> 16) | (hi & 0xffff0000u);
            lo = cva.w; hi = cvb.w;
            bp[base + 120] = (lo & 0xffffu) | (hi << 16);
            bp[base + 140] = (lo >> 16) | (hi & 0xffff0000u);
        }
        if (k0 + 32 < TT) {
            pga = *(const uint4*)(Gb + (size_t)(t0 + lr) * TT + k0 + 32 + c8);
            if (tid < 128) {
                cva = *(const uint4*)(nab + (size_t)(k0 + 32 + 2 * spair) * DD + e0 + eg * 8);
                cvb = *(const uint4*)(nab + (size_t)(k0 + 32 + 2 * spair + 1) * DD + e0 + eg * 8);
            }
        }
        __syncthreads();
        short8 af[2], bfr[2];
        af[0]  = *(const short8*)&As[(wm * 32 + ln) * 40 + quad * 8];
        af[1]  = *(const short8*)&As[(wm * 32 + 16 + ln) * 40 + quad * 8];
        bfr[0] = *(const short8*)&Bs[(wn * 32 + ln) * 40 + quad * 8];
        bfr[1] = *(const short8*)&Bs[(wn * 32 + 16 + ln) * 40 + quad * 8];
#pragma unroll
        for (int i = 0; i < 2; ++i)
#pragma unroll
            for (int j = 0; j < 2; ++j)
                acc[i][j] = __builtin_amdgcn_mfma_f32_16x16x32_bf16(
                    af[i], bfr[j], acc[i][j], 0, 0, 0);
        __syncthreads();
    }

    // stage na[t0..t0+63][e0..e0+63] into LDS (stride 72 shorts)
    unsigned short* Ns = AB;
    {
        const int r0_ = tid >> 3, k8 = (tid & 7) * 8;
        *(uint4*)&Ns[r0_ * 72 + k8] =
            *(const uint4*)(nab + (size_t)(t0 + r0_) * DD + e0 + k8);
        const int c1 = tid + 256;
        const int r1_ = c1 >> 3, k8b = (c1 & 7) * 8;
        *(uint4*)&Ns[r1_ * 72 + k8b] =
            *(const uint4*)(nab + (size_t)(t0 + r1_) * DD + e0 + k8b);
    }
    if (tid < 64) qsum[tid] = 0.f;
    __syncthreads();

    unsigned short* Hb = H + (size_t)bz * TT * DD;
#pragma unroll
    for (int j = 0; j < 2; ++j) {
        const int col  = e0 + wn * 32 + j * 16 + ln;
        const int lcol = wn * 32 + j * 16 + ln;
        float qp = 0.f;
#pragma unroll
        for (int i = 0; i < 2; ++i) {
            const int row0  = t0 + wm * 32 + i * 16 + quad * 4;
            const int lrow0 = wm * 32 + i * 16 + quad * 4;
#pragma unroll
            for (int r = 0; r < 4; r += 2) {
                const float hv0 = acc[i][j][r];
                const float hv1 = acc[i][j][r + 1];
                const unsigned pk = pk2(hv0, hv1);
                Hb[(size_t)(row0 + r) * DD + col] = (unsigned short)pk;
                Hb[(size_t)(row0 + r + 1) * DD + col] = (unsigned short)(pk >> 16);
                qp = fmaf(bf2f(Ns[(lrow0 + r) * 72 + lcol]), hv0, qp);
                qp = fmaf(bf2f(Ns[(lrow0 + r + 1) * 72 + lcol]), hv1, qp);
            }
        }
        qp += __shfl_xor(qp, 16);
        qp += __shfl_xor(qp, 32);
        if (quad == 0) atomicAdd(&qsum[wn * 32 + j * 16 + ln], qp);
    }
    __syncthreads();
    if (tid < 64) atomicAdd(q + bz * DD + e0 + tid, qsum[tid]);
}

// ---------------------------------------------------------------------------
// K4: persp via MFMA, split-K over 4 waves, k-loop unrolled. [round-8 verbatim]
// grid: (T/16, B), 256 thr.
// ---------------------------------------------------------------------------
__global__ __launch_bounds__(256)
void k_persp_mfma(const unsigned short* __restrict__ na,
                  const unsigned short* __restrict__ H,
                  const float* __restrict__ q,
                  const unsigned short* __restrict__ W2,
                  float* __restrict__ out) {
    const int b    = blockIdx.y;
    const int r0   = blockIdx.x * 16;
    const int wave = threadIdx.x >> 6;   // 0..3
    const int lane = threadIdx.x & 63;
    const int quad = lane >> 4, ln = lane & 15;
    const size_t rowbase = ((size_t)b * TT + r0 + ln) * DD;

    __shared__ float qs[DD];
    __shared__ float ps[3][64][24];      // waves 1..3 partials
    {
        const float* qb = q + (size_t)b * DD;
        float2 v = *(const float2*)(qb + 2 * threadIdx.x);
        qs[2 * threadIdx.x + 0] = rsqrtf(fmaxf(v.x, EPSF));
        qs[2 * threadIdx.x + 1] = rsqrtf(fmaxf(v.y, EPSF));
    }
    __syncthreads();

    f32x4 s1[2], s2[2], s3[2];
#pragma unroll
    for (int j = 0; j < 2; ++j)
#pragma unroll
        for (int r = 0; r < 4; ++r) { s1[j][r] = 0.f; s2[j][r] = 0.f; s3[j][r] = 0.f; }

    const int kbeg = wave * 128;
#pragma unroll
    for (int ki = 0; ki < 4; ++ki) {
        const int k0 = kbeg + ki * 32;
        const int k = k0 + quad * 8;
        uint4 au = *(const uint4*)(na + rowbase + k);
        uint4 hu = *(const uint4*)(H + rowbase + k);
        float4 q0 = *(const float4*)&qs[k];
        float4 q1 = *(const float4*)&qs[k + 4];
        const float av[8] = {bf2f(au.x & 0xffffu), bf2f(au.x >> 16),
                             bf2f(au.y & 0xffffu), bf2f(au.y >> 16),
                             bf2f(au.z & 0xffffu), bf2f(au.z >> 16),
                             bf2f(au.w & 0xffffu), bf2f(au.w >> 16)};
        const float qv[8] = {q0.x, q0.y, q0.z, q0.w, q1.x, q1.y, q1.z, q1.w};
        float hv[8] = {bf2f(hu.x & 0xffffu), bf2f(hu.x >> 16),
                       bf2f(hu.y & 0xffffu), bf2f(hu.y >> 16),
                       bf2f(hu.z & 0xffffu), bf2f(hu.z >> 16),
                       bf2f(hu.w & 0xffffu), bf2f(hu.w >> 16)};
#pragma unroll
        for (int t = 0; t < 8; ++t) hv[t] *= qv[t];
        U8 ah, aa, hh;
        ah.u.x = pk2(av[0] * hv[0], av[1] * hv[1]);
        ah.u.y = pk2(av[2] * hv[2], av[3] * hv[3]);
        ah.u.z = pk2(av[4] * hv[4], av[5] * hv[5]);
        ah.u.w = pk2(av[6] * hv[6], av[7] * hv[7]);
        aa.u.x = pk2(av[0] * av[0], av[1] * av[1]);
        aa.u.y = pk2(av[2] * av[2], av[3] * av[3]);
        aa.u.z = pk2(av[4] * av[4], av[5] * av[5]);
        aa.u.w = pk2(av[6] * av[6], av[7] * av[7]);
        hh.u.x = pk2(hv[0] * hv[0], hv[1] * hv[1]);
        hh.u.y = pk2(hv[2] * hv[2], hv[3] * hv[3]);
        hh.u.z = pk2(hv[4] * hv[4], hv[5] * hv[5]);
        hh.u.w = pk2(hv[6] * hv[6], hv[7] * hv[7]);
        short8 bw0 = *(const short8*)(W2 + (size_t)ln * DD + k);
        short8 bw1 = *(const short8*)(W2 + (size_t)(16 + ln) * DD + k);
        s1[0] = __builtin_amdgcn_mfma_f32_16x16x32_bf16(ah.s, bw0, s1[0], 0, 0, 0);
        s1[1] = __builtin_amdgcn_mfma_f32_16x16x32_bf16(ah.s, bw1, s1[1], 0, 0, 0);
        s2[0] = __builtin_amdgcn_mfma_f32_16x16x32_bf16(aa.s, bw0, s2[0], 0, 0, 0);
        s2[1] = __builtin_amdgcn_mfma_f32_16x16x32_bf16(aa.s, bw1, s2[1], 0, 0, 0);
        s3[0] = __builtin_amdgcn_mfma_f32_16x16x32_bf16(hh.s, bw0, s3[0], 0, 0, 0);
        s3[1] = __builtin_amdgcn_mfma_f32_16x16x32_bf16(hh.s, bw1, s3[1], 0, 0, 0);
    }

    if (wave >= 1) {
#pragma unroll
        for (int j = 0; j < 2; ++j)
#pragma unroll
            for (int r = 0; r < 4; ++r) {
                ps[wave - 1][lane][j * 4 + r]      = s1[j][r];
                ps[wave - 1][lane][8 + j * 4 + r]  = s2[j][r];
                ps[wave - 1][lane][16 + j * 4 + r] = s3[j][r];
            }
    }
    __syncthreads();
    if (wave == 0) {
#pragma unroll
        for (int j = 0; j < 2; ++j) {
            const int p = j * 16 + ln;
            if (p < PP) {
#pragma unroll
                for (int r = 0; r < 4; ++r) {
                    const float v1 = s1[j][r] + ps[0][lane][j * 4 + r]
                                   + ps[1][lane][j * 4 + r] + ps[2][lane][j * 4 + r];
                    const float v2 = s2[j][r] + ps[0][lane][8 + j * 4 + r]
                                   + ps[1][lane][8 + j * 4 + r] + ps[2][lane][8 + j * 4 + r];
                    const float v3 = s3[j][r] + ps[0][lane][16 + j * 4 + r]
                                   + ps[1][lane][16 + j * 4 + r] + ps[2][lane][16 + j * 4 + r];
                    const size_t row = (size_t)b * TT + r0 + quad * 4 + r;
                    const float v = v1 * rsqrtf(fmaxf(v2, EPSF))
                                       * rsqrtf(fmaxf(v3, EPSF));
                    out[row * PP + p] = v;
                    out[(size_t)BTP + row * PP + p] = v;
                }
            }
        }
    }
}

// ---------------------------------------------------------------------------
extern "C" void kernel_launch(void* const* d_in, const int* in_sizes, int n_in,
                              void* d_out, int out_size, void* d_ws, size_t ws_size,
                              hipStream_t stream) {
    (void)in_sizes; (void)n_in; (void)out_size; (void)ws_size;
    const float* a = (const float*)d_in[0];   // (B,T,D)
    const float* b = (const float*)d_in[1];   // (B,T,D)
    const float* W = (const float*)d_in[2];   // (P,D)
    float* out = (float*)d_out;

    char* ws = (char*)d_ws;
    unsigned short* nb_bf = (unsigned short*)ws;                       // 8 MB
    unsigned short* na_bf = (unsigned short*)(ws + (8u << 20));        // 8 MB
    unsigned short* G_bf  = (unsigned short*)(ws + (16u << 20));       // 4 MB
    unsigned short* H_bf  = (unsigned short*)(ws + (20u << 20));       // 8 MB
    float* q     = (float*)(ws + (28u << 20));                         // 64 KB
    unsigned short* W2 = (unsigned short*)(ws + (28u << 20) + (64u << 10)); // 32 KB

    // L1: b-norm -> nb_bf + q zero + W2 build (halved prep)
    k_prep_b<<<BB * TT / 4, 256, 0, stream>>>(b, W, nb_bf, q, W2);

    // L2: G tiles (blocks 0..511) ∥ a-norm -> na_bf (blocks 512..1023)
    k_g_pa<<<1024, 256, 0, stream>>>(nb_bf, a, G_bf, na_bf);

    // L3: H = G na (b32-pack staging, reg-prefetch), fused q
    dim3 gH(DD / 64, TT / 64, BB);
    k_gemm_h<<<gH, 256, 0, stream>>>(G_bf, na_bf, H_bf, q);

    // L4: perspective outputs (invq inlined, split-K over 4 waves, unrolled)
    dim3 gP(TT / 16, BB);
    k_persp_mfma<<<gP, 256, 0, stream>>>(na_bf, H_bf, q, W2, out);
}